// Round 3
// baseline (313.135 us; speedup 1.0000x reference)
//
#include <hip/hip_runtime.h>

// GAT layer fused, MI355X gfx950 — v3: LDS-staged flash with row reuse.
// conv_h(h->hQf frags) | pack_wf | count_k -> hnew_k(hQf,Wf->hnb,hnV frags)
// -> attn_part (128 rows/block, 4 waves x 32 rows, double-buffered LDS tiles,
//    S=16 j-chunks, bf16 partials) -> comb_k.

typedef __attribute__((ext_vector_type(8))) short short8;   // 8 x bf16 (4 VGPR)
typedef __attribute__((ext_vector_type(4))) float f32x4;    // MFMA C/D frag

#define NN 8192
#define DD 256
#define NEGB -1.2983e16f  // -9e15 * log2(e): NEG_BIG in base-2 softmax domain

__device__ __forceinline__ unsigned short f2bf(float f) {
  unsigned u = __builtin_bit_cast(unsigned, f);
  u += 0x7FFFu + ((u >> 16) & 1u);  // RNE
  return (unsigned short)(u >> 16);
}
__device__ __forceinline__ float bf2f(unsigned short s) {
  unsigned u = ((unsigned)s) << 16;
  return __builtin_bit_cast(float, u);
}
__device__ __forceinline__ f32x4 mfma16(short8 a, short8 b, f32x4 c) {
  return __builtin_amdgcn_mfma_f32_16x16x32_bf16(a, b, c, 0, 0, 0);
}
// async global->LDS, 16B per lane; lds ptr must be wave-uniform base
__device__ __forceinline__ void gld16(const unsigned short* g, unsigned short* l) {
  __builtin_amdgcn_global_load_lds(
      (const __attribute__((address_space(1))) void*)g,
      (__attribute__((address_space(3))) void*)l, 16, 0, 0);
}

// ---- k = sum(adj[:,0] != 0) ------------------------------------------------
__global__ __launch_bounds__(256) void count_k(const int* __restrict__ adj,
                                               int* __restrict__ kout) {
  __shared__ int red[256];
  int gid = blockIdx.x * 256 + threadIdx.x;
  red[threadIdx.x] = (adj[(size_t)gid * NN] != 0);
  __syncthreads();
  for (int off = 128; off; off >>= 1) {
    if (threadIdx.x < off) red[threadIdx.x] += red[threadIdx.x + off];
    __syncthreads();
  }
  if (threadIdx.x == 0) atomicAdd(kout, red[0]);
}

// ---- h (f32) -> hQf (bf16 MFMA B/A frags, frag-major) ---------------------
// hQf[((j16*8+kk)*64 + l)*8 + e] = h[j16*16 + (l&15)][kk*32 + (l>>4)*8 + e]
__global__ __launch_bounds__(256) void conv_h(const float* __restrict__ h,
                                              unsigned short* __restrict__ hQf) {
  int gid = blockIdx.x * 256 + threadIdx.x;  // 524288
  int i = gid >> 6, k4 = (gid & 63) * 4;
  float4 v = *(const float4*)(h + (size_t)i * DD + k4);
  size_t off = ((size_t)((i >> 4) * 8 + (k4 >> 5)) * 64 +
                (((k4 >> 3) & 3) * 16 + (i & 15))) * 8 + (k4 & 7);
  ushort4 o;
  o.x = f2bf(v.x); o.y = f2bf(v.y); o.z = f2bf(v.z); o.w = f2bf(v.w);
  *(ushort4*)(hQf + off) = o;
}

// ---- W (f32 [256][256]) -> bf16 B-frags ------------------------------------
__global__ __launch_bounds__(256) void pack_wf(const float* __restrict__ W,
                                               unsigned short* __restrict__ Wf) {
  int gid = blockIdx.x * 256 + threadIdx.x;  // 8192 total
  int l = gid & 63, f = gid >> 6, n16 = f >> 3, kk = f & 7;
  int lr = l & 15, lg = l >> 4;
  const float* src = W + (size_t)(n16 * 16 + lr) * DD + kk * 32 + lg * 8;
  float4 w0 = *(const float4*)src, w1 = *(const float4*)(src + 4);
  short8 o;
  o[0] = (short)f2bf(w0.x); o[1] = (short)f2bf(w0.y);
  o[2] = (short)f2bf(w0.z); o[3] = (short)f2bf(w0.w);
  o[4] = (short)f2bf(w1.x); o[5] = (short)f2bf(w1.y);
  o[6] = (short)f2bf(w1.z); o[7] = (short)f2bf(w1.w);
  *(short8*)(Wf + (size_t)gid * 8) = o;
}

// ---- h_new = h @ W^T + b -> hnb (row-major) + hnV (PV B-frags) ------------
__global__ __launch_bounds__(256) void hnew_k(const unsigned short* __restrict__ hQf,
                                              const unsigned short* __restrict__ Wf,
                                              const float* __restrict__ bias,
                                              unsigned short* __restrict__ hnb,
                                              unsigned short* __restrict__ hnV) {
  const int tid = threadIdx.x, w = tid >> 6, l = tid & 63, lr = l & 15, lg = l >> 4;
  const int row0 = blockIdx.x * 64 + w * 16;

  short8 a[8];
#pragma unroll
  for (int kk = 0; kk < 8; ++kk)
    a[kk] = *(const short8*)(hQf + ((size_t)((row0 >> 4) * 8 + kk) * 64 + l) * 8);

  f32x4 acc[16];
#pragma unroll
  for (int nt = 0; nt < 16; ++nt) acc[nt] = (f32x4){0.f, 0.f, 0.f, 0.f};

#pragma unroll
  for (int kk = 0; kk < 8; ++kk)
#pragma unroll
    for (int nt = 0; nt < 16; ++nt) {
      short8 bf = *(const short8*)(Wf + ((size_t)(nt * 8 + kk) * 64 + l) * 8);
      acc[nt] = mfma16(a[kk], bf, acc[nt]);
    }
#pragma unroll
  for (int nt = 0; nt < 16; ++nt) {
    const int col = nt * 16 + lr;
    const float bv = bias[col];
#pragma unroll
    for (int q = 0; q < 4; ++q) {
      const int row = row0 + lg * 4 + q;
      unsigned short r16 = f2bf(acc[nt][q] + bv);
      hnb[(size_t)row * DD + col] = r16;
      hnV[((size_t)((row >> 5) * 16 + nt) * 64 + ((row >> 3) & 3) * 16 + lr) * 8 +
          (row & 7)] = r16;
    }
  }
}

// ---- flash attention partials ---------------------------------------------
// Block (bx=row-block of 128, by=chunk c): 4 waves x 32 rows. Per j-tile (32
// cols): stage K-frags (16KB) + V-frags (16KB) into LDS (double-buffered,
// global_load_lds), all waves consume with 2x row-subtile register reuse.
__global__ __launch_bounds__(256, 2) void attn_part(
    const unsigned short* __restrict__ hQf, const unsigned short* __restrict__ hnV,
    const int* __restrict__ adj, const int* __restrict__ kptr,
    float* __restrict__ pm, float* __restrict__ pl, unsigned short* __restrict__ pO,
    int T) {
  __shared__ __align__(16) unsigned short sK[2][8192];       // 16KB x2
  __shared__ __align__(16) unsigned short sV[2][8192];       // 16KB x2
  __shared__ __align__(16) unsigned short sP[4][2][16][40];  // per-wave P transpose

  const int tid = threadIdx.x, w = tid >> 6, l = tid & 63, lr = l & 15, lg = l >> 4;
  const int i0 = blockIdx.x * 128, c = blockIdx.y;
  const int kid = *kptr;
  if (i0 + 128 <= kid) return;  // whole block identity: comb_k handles it

  const int r0 = i0 + w * 32;  // this wave's 32 rows

  short8 qf[2][8];  // Q A-frags, 2 row-subtiles
#pragma unroll
  for (int rt = 0; rt < 2; ++rt)
#pragma unroll
    for (int kk = 0; kk < 8; ++kk)
      qf[rt][kk] =
          *(const short8*)(hQf + ((size_t)(((r0 >> 4) + rt) * 8 + kk) * 64 + l) * 8);

  f32x4 Oacc[2][16];
#pragma unroll
  for (int rt = 0; rt < 2; ++rt)
#pragma unroll
    for (int nt = 0; nt < 16; ++nt) Oacc[rt][nt] = (f32x4){0.f, 0.f, 0.f, 0.f};
  float m2[2][4], lsum[2][4];
#pragma unroll
  for (int rt = 0; rt < 2; ++rt)
#pragma unroll
    for (int q = 0; q < 4; ++q) { m2[rt][q] = NEGB; lsum[rt][q] = 0.f; }
  const float c1 = 0.09016844005556021f;  // log2(e)/sqrt(256)

  const int jt0 = c * T;

  // ---- prologue: stage tile jt0, load its adj ----
  {
    const unsigned short* srcK = hQf + (size_t)jt0 * 8192;
    const unsigned short* srcV = hnV + (size_t)jt0 * 8192;
#pragma unroll
    for (int it = 0; it < 4; ++it) {
      int eo = (it * 256 + w * 64) * 8;
      gld16(srcK + eo + l * 8, &sK[0][eo]);
      gld16(srcV + eo + l * 8, &sV[0][eo]);
    }
  }
  int avc[16];
#pragma unroll
  for (int rt = 0; rt < 2; ++rt)
#pragma unroll
    for (int nt = 0; nt < 2; ++nt)
#pragma unroll
      for (int q = 0; q < 4; ++q)
        avc[(rt * 2 + nt) * 4 + q] =
            adj[(size_t)(r0 + rt * 16 + lg * 4 + q) * NN + jt0 * 32 + nt * 16 + lr];
  __syncthreads();

  for (int t = 0; t < T; ++t) {
    const int cur = t & 1;
    int avn[16];
    if (t + 1 < T) {  // stage next tile + prefetch next adj
      const int jn = jt0 + t + 1;
      const unsigned short* srcK = hQf + (size_t)jn * 8192;
      const unsigned short* srcV = hnV + (size_t)jn * 8192;
#pragma unroll
      for (int it = 0; it < 4; ++it) {
        int eo = (it * 256 + w * 64) * 8;
        gld16(srcK + eo + l * 8, &sK[cur ^ 1][eo]);
        gld16(srcV + eo + l * 8, &sV[cur ^ 1][eo]);
      }
#pragma unroll
      for (int rt = 0; rt < 2; ++rt)
#pragma unroll
        for (int nt = 0; nt < 2; ++nt)
#pragma unroll
          for (int q = 0; q < 4; ++q)
            avn[(rt * 2 + nt) * 4 + q] =
                adj[(size_t)(r0 + rt * 16 + lg * 4 + q) * NN + jn * 32 + nt * 16 + lr];
    }

    // ---- S = Q . K^T (K=256), B-frags from LDS reused across 2 row-subtiles
    f32x4 S[2][2];
    S[0][0] = (f32x4){0.f, 0.f, 0.f, 0.f}; S[0][1] = (f32x4){0.f, 0.f, 0.f, 0.f};
    S[1][0] = (f32x4){0.f, 0.f, 0.f, 0.f}; S[1][1] = (f32x4){0.f, 0.f, 0.f, 0.f};
#pragma unroll
    for (int kk = 0; kk < 8; ++kk)
#pragma unroll
      for (int nt = 0; nt < 2; ++nt) {
        short8 bf = *(const short8*)(&sK[cur][(nt * 8 + kk) * 512 + l * 8]);
        S[0][nt] = mfma16(qf[0][kk], bf, S[0][nt]);
        S[1][nt] = mfma16(qf[1][kk], bf, S[1][nt]);
      }

    // ---- masked online softmax (base-2), per row-subtile ----
#pragma unroll
    for (int rt = 0; rt < 2; ++rt) {
      float sv0[4], sv1[4], mt[4];
#pragma unroll
      for (int q = 0; q < 4; ++q) {
        sv0[q] = avc[(rt * 2 + 0) * 4 + q] ? S[rt][0][q] * c1 : NEGB;
        sv1[q] = avc[(rt * 2 + 1) * 4 + q] ? S[rt][1][q] * c1 : NEGB;
        mt[q] = fmaxf(sv0[q], sv1[q]);
      }
#pragma unroll
      for (int q = 0; q < 4; ++q)
#pragma unroll
        for (int off = 1; off < 16; off <<= 1)
          mt[q] = fmaxf(mt[q], __shfl_xor(mt[q], off));
      float fac[4];
#pragma unroll
      for (int q = 0; q < 4; ++q) {
        float mn = fmaxf(m2[rt][q], mt[q]);
        fac[q] = __builtin_amdgcn_exp2f(m2[rt][q] - mn);
        sv0[q] = __builtin_amdgcn_exp2f(sv0[q] - mn);
        sv1[q] = __builtin_amdgcn_exp2f(sv1[q] - mn);
        m2[rt][q] = mn;
      }
      float rs[4];
#pragma unroll
      for (int q = 0; q < 4; ++q) {
        rs[q] = sv0[q] + sv1[q];
#pragma unroll
        for (int off = 1; off < 16; off <<= 1) rs[q] += __shfl_xor(rs[q], off);
        lsum[rt][q] = lsum[rt][q] * fac[q] + rs[q];
      }
#pragma unroll
      for (int nt = 0; nt < 16; ++nt)
#pragma unroll
        for (int q = 0; q < 4; ++q) Oacc[rt][nt][q] *= fac[q];
#pragma unroll
      for (int q = 0; q < 4; ++q) {
        sP[w][rt][lg * 4 + q][lr] = f2bf(sv0[q]);
        sP[w][rt][lg * 4 + q][16 + lr] = f2bf(sv1[q]);
      }
    }

    // ---- PV: V-frags from LDS, reused across 2 row-subtiles ----
    short8 pa0 = *(const short8*)(&sP[w][0][lr][lg * 8]);
    short8 pa1 = *(const short8*)(&sP[w][1][lr][lg * 8]);
#pragma unroll
    for (int cnt = 0; cnt < 16; ++cnt) {
      short8 vf = *(const short8*)(&sV[cur][cnt * 512 + l * 8]);
      Oacc[0][cnt] = mfma16(pa0, vf, Oacc[0][cnt]);
      Oacc[1][cnt] = mfma16(pa1, vf, Oacc[1][cnt]);
    }

#pragma unroll
    for (int x = 0; x < 16; ++x) avc[x] = avn[x];
    __syncthreads();  // drains next-stage vmcnt + protects buffers
  }

  // ---- write chunk partials (bf16 O, f32 m/l) ----
#pragma unroll
  for (int rt = 0; rt < 2; ++rt)
#pragma unroll
    for (int q = 0; q < 4; ++q) {
      int row = r0 + rt * 16 + lg * 4 + q;
      if (lr == 0) {
        pm[(size_t)c * NN + row] = m2[rt][q];
        pl[(size_t)c * NN + row] = lsum[rt][q];
      }
    }
#pragma unroll
  for (int cnt = 0; cnt < 16; ++cnt)
#pragma unroll
    for (int rt = 0; rt < 2; ++rt)
#pragma unroll
      for (int q = 0; q < 4; ++q) {
        int row = r0 + rt * 16 + lg * 4 + q;
        pO[((size_t)c * NN + row) * DD + cnt * 16 + lr] = f2bf(Oacc[rt][cnt][q]);
      }
}

// ---- combine chunks + epilogue: one block per row -------------------------
__global__ __launch_bounds__(256) void comb_k(const float* __restrict__ pm,
                                              const float* __restrict__ pl,
                                              const unsigned short* __restrict__ pO,
                                              const unsigned short* __restrict__ hnb,
                                              const int* __restrict__ kptr,
                                              float* __restrict__ out, int S) {
  const int row = blockIdx.x, col = threadIdx.x;
  const int kid = *kptr;
  float v = bf2f(hnb[(size_t)row * DD + col]);
  float res;
  if (row < kid) {
    res = v;
  } else {
    float M = NEGB;
    for (int cc = 0; cc < S; ++cc) M = fmaxf(M, pm[(size_t)cc * NN + row]);
    float L = 0.f, acc = 0.f;
    for (int cc = 0; cc < S; ++cc) {
      float f = __builtin_amdgcn_exp2f(pm[(size_t)cc * NN + row] - M);
      L += pl[(size_t)cc * NN + row] * f;
      acc += bf2f(pO[((size_t)cc * NN + row) * DD + col]) * f;
    }
    res = acc * (0.5f / L) + 0.5f * v;
  }
  out[(size_t)row * DD + col] = fmaxf(res, 0.f);
}

extern "C" void kernel_launch(void* const* d_in, const int* in_sizes, int n_in,
                              void* d_out, int out_size, void* d_ws, size_t ws_size,
                              hipStream_t stream) {
  const float* h = (const float*)d_in[0];
  const int* adj = (const int*)d_in[1];
  const float* W = (const float*)d_in[2];
  const float* b = (const float*)d_in[3];
  float* out = (float*)d_out;

  char* ws = (char*)d_ws;
  const size_t MB4 = (size_t)NN * DD * 2;  // 4 MiB
  int* kbuf = (int*)ws;
  unsigned short* hQf = (unsigned short*)(ws + 256);
  unsigned short* hnb = (unsigned short*)(ws + 256 + MB4);
  unsigned short* hnV = (unsigned short*)(ws + 256 + 2 * MB4);
  unsigned short* Wf = (unsigned short*)(ws + 256 + 3 * MB4);  // 128 KiB
  char* dyn = ws + 256 + 3 * MB4 + (256 << 10);

  size_t fixed = 256 + 3 * MB4 + (256 << 10);
  int S = 16;
  while (S > 1 && fixed + (size_t)S * NN * (DD * 2 + 8) > ws_size) S >>= 1;
  const int T = 256 / S;

  float* pm = (float*)dyn;
  float* pl = pm + (size_t)S * NN;
  unsigned short* pO = (unsigned short*)(pl + (size_t)S * NN);

  hipMemsetAsync(kbuf, 0, 4, stream);
  hipLaunchKernelGGL(count_k, dim3(32), dim3(256), 0, stream, adj, kbuf);
  hipLaunchKernelGGL(conv_h, dim3(2048), dim3(256), 0, stream, h, hQf);
  hipLaunchKernelGGL(pack_wf, dim3(32), dim3(256), 0, stream, W, Wf);
  hipLaunchKernelGGL(hnew_k, dim3(NN / 64), dim3(256), 0, stream, hQf, Wf, b, hnb, hnV);
  hipLaunchKernelGGL(attn_part, dim3(NN / 128, S), dim3(256), 0, stream,
                     hQf, hnV, adj, kbuf, pm, pl, pO, T);
  hipLaunchKernelGGL(comb_k, dim3(NN), dim3(256), 0, stream, pm, pl, pO, hnb, kbuf, out, S);
}

// Round 4
// 222.582 us; speedup vs baseline: 1.4068x; 1.4068x over previous
//
#include <hip/hip_runtime.h>

// GAT layer fused, MI355X gfx950 — v4: spill-free 16-rows/wave flash,
// 512-thread blocks (8 waves), LDS-staged K/V frag tiles, CU-balancing block
// swizzle, defer-max softmax. Pipeline: count_k | conv_h | pack_wf -> hnew_k
// -> attn_part (S=8 chunks) -> comb_k.

typedef __attribute__((ext_vector_type(8))) short short8;   // 8 x bf16 (4 VGPR)
typedef __attribute__((ext_vector_type(4))) float f32x4;    // MFMA C/D frag

#define NN 8192
#define DD 256
#define NEGB -1.2983e16f  // -9e15 * log2(e): NEG_BIG in base-2 softmax domain

__device__ __forceinline__ unsigned short f2bf(float f) {
  unsigned u = __builtin_bit_cast(unsigned, f);
  u += 0x7FFFu + ((u >> 16) & 1u);  // RNE
  return (unsigned short)(u >> 16);
}
__device__ __forceinline__ float bf2f(unsigned short s) {
  unsigned u = ((unsigned)s) << 16;
  return __builtin_bit_cast(float, u);
}
__device__ __forceinline__ f32x4 mfma16(short8 a, short8 b, f32x4 c) {
  return __builtin_amdgcn_mfma_f32_16x16x32_bf16(a, b, c, 0, 0, 0);
}
// async global->LDS, 16B per lane; lds ptr wave-uniform base
__device__ __forceinline__ void gld16(const unsigned short* g, unsigned short* l) {
  __builtin_amdgcn_global_load_lds(
      (const __attribute__((address_space(1))) void*)g,
      (__attribute__((address_space(3))) void*)l, 16, 0, 0);
}

// ---- k = sum(adj[:,0] != 0) ------------------------------------------------
__global__ __launch_bounds__(256) void count_k(const int* __restrict__ adj,
                                               int* __restrict__ kout) {
  __shared__ int red[256];
  int gid = blockIdx.x * 256 + threadIdx.x;
  red[threadIdx.x] = (adj[(size_t)gid * NN] != 0);
  __syncthreads();
  for (int off = 128; off; off >>= 1) {
    if (threadIdx.x < off) red[threadIdx.x] += red[threadIdx.x + off];
    __syncthreads();
  }
  if (threadIdx.x == 0) atomicAdd(kout, red[0]);
}

// ---- h (f32) -> hQf (bf16 MFMA A/B frags, frag-major) ---------------------
// hQf[((j16*8+kk)*64 + l)*8 + e] = h[j16*16 + (l&15)][kk*32 + (l>>4)*8 + e]
__global__ __launch_bounds__(256) void conv_h(const float* __restrict__ h,
                                              unsigned short* __restrict__ hQf) {
  int gid = blockIdx.x * 256 + threadIdx.x;  // 524288
  int i = gid >> 6, k4 = (gid & 63) * 4;
  float4 v = *(const float4*)(h + (size_t)i * DD + k4);
  size_t off = ((size_t)((i >> 4) * 8 + (k4 >> 5)) * 64 +
                (((k4 >> 3) & 3) * 16 + (i & 15))) * 8 + (k4 & 7);
  ushort4 o;
  o.x = f2bf(v.x); o.y = f2bf(v.y); o.z = f2bf(v.z); o.w = f2bf(v.w);
  *(ushort4*)(hQf + off) = o;
}

// ---- W (f32 [256][256]) -> bf16 B-frags ------------------------------------
__global__ __launch_bounds__(256) void pack_wf(const float* __restrict__ W,
                                               unsigned short* __restrict__ Wf) {
  int gid = blockIdx.x * 256 + threadIdx.x;  // 8192 total
  int l = gid & 63, f = gid >> 6, n16 = f >> 3, kk = f & 7;
  int lr = l & 15, lg = l >> 4;
  const float* src = W + (size_t)(n16 * 16 + lr) * DD + kk * 32 + lg * 8;
  float4 w0 = *(const float4*)src, w1 = *(const float4*)(src + 4);
  short8 o;
  o[0] = (short)f2bf(w0.x); o[1] = (short)f2bf(w0.y);
  o[2] = (short)f2bf(w0.z); o[3] = (short)f2bf(w0.w);
  o[4] = (short)f2bf(w1.x); o[5] = (short)f2bf(w1.y);
  o[6] = (short)f2bf(w1.z); o[7] = (short)f2bf(w1.w);
  *(short8*)(Wf + (size_t)gid * 8) = o;
}

// ---- h_new = h @ W^T + b -> hnb (row-major) + hnV (PV B-frags) ------------
__global__ __launch_bounds__(256) void hnew_k(const unsigned short* __restrict__ hQf,
                                              const unsigned short* __restrict__ Wf,
                                              const float* __restrict__ bias,
                                              unsigned short* __restrict__ hnb,
                                              unsigned short* __restrict__ hnV) {
  const int tid = threadIdx.x, w = tid >> 6, l = tid & 63, lr = l & 15, lg = l >> 4;
  const int row0 = blockIdx.x * 64 + w * 16;

  short8 a[8];
#pragma unroll
  for (int kk = 0; kk < 8; ++kk)
    a[kk] = *(const short8*)(hQf + ((size_t)((row0 >> 4) * 8 + kk) * 64 + l) * 8);

  f32x4 acc[16];
#pragma unroll
  for (int nt = 0; nt < 16; ++nt) acc[nt] = (f32x4){0.f, 0.f, 0.f, 0.f};

#pragma unroll
  for (int kk = 0; kk < 8; ++kk)
#pragma unroll
    for (int nt = 0; nt < 16; ++nt) {
      short8 bf = *(const short8*)(Wf + ((size_t)(nt * 8 + kk) * 64 + l) * 8);
      acc[nt] = mfma16(a[kk], bf, acc[nt]);
    }
#pragma unroll
  for (int nt = 0; nt < 16; ++nt) {
    const int col = nt * 16 + lr;
    const float bv = bias[col];
#pragma unroll
    for (int q = 0; q < 4; ++q) {
      const int row = row0 + lg * 4 + q;
      unsigned short r16 = f2bf(acc[nt][q] + bv);
      hnb[(size_t)row * DD + col] = r16;
      hnV[((size_t)((row >> 5) * 16 + nt) * 64 + ((row >> 3) & 3) * 16 + lr) * 8 +
          (row & 7)] = r16;
    }
  }
}

// ---- flash attention partials ---------------------------------------------
// Block (bx,by): 8 waves x 16 rows = 128 rows, chunk by (T j-tiles). ebx
// swizzle balances working blocks across CUs. Double-buffered LDS K/V tiles
// via global_load_lds; adj prefetched one tile ahead; defer-max softmax.
__global__ __launch_bounds__(512, 2) void attn_part(
    const unsigned short* __restrict__ hQf, const unsigned short* __restrict__ hnV,
    const int* __restrict__ adj, const int* __restrict__ kptr,
    float* __restrict__ pm, float* __restrict__ pl, unsigned short* __restrict__ pO,
    int T) {
  __shared__ __align__(16) unsigned short sK[2][8192];  // 16KB x2
  __shared__ __align__(16) unsigned short sV[2][8192];  // 16KB x2
  __shared__ __align__(16) unsigned short sP[8][16][40];  // per-wave P transpose

  const int tid = threadIdx.x, w = tid >> 6, l = tid & 63, lr = l & 15, lg = l >> 4;
  const int ebx = (blockIdx.x + blockIdx.y * 8) & 63;  // CU balance swizzle
  const int i0 = ebx * 128, c = blockIdx.y;
  const int kid = *kptr;
  if (i0 + 128 <= kid) return;  // whole block identity: comb_k handles it

  const int r0 = i0 + w * 16;  // this wave's 16 rows

  short8 qf[8];  // Q A-frags
#pragma unroll
  for (int kk = 0; kk < 8; ++kk)
    qf[kk] = *(const short8*)(hQf + ((size_t)((r0 >> 4) * 8 + kk) * 64 + l) * 8);

  f32x4 Oacc[16];
#pragma unroll
  for (int nt = 0; nt < 16; ++nt) Oacc[nt] = (f32x4){0.f, 0.f, 0.f, 0.f};
  float m2[4] = {NEGB, NEGB, NEGB, NEGB};
  float lsum[4] = {0.f, 0.f, 0.f, 0.f};
  const float c1 = 0.09016844005556021f;  // log2(e)/sqrt(256)

  const int jt0 = c * T;
  size_t arow[4];
#pragma unroll
  for (int q = 0; q < 4; ++q) arow[q] = (size_t)(r0 + lg * 4 + q) * NN;

  // ---- prologue: stage tile jt0 (wave w stages segments w*2, w*2+1) ----
  {
    const unsigned short* srcK = hQf + (size_t)jt0 * 8192;
    const unsigned short* srcV = hnV + (size_t)jt0 * 8192;
#pragma unroll
    for (int s = 0; s < 2; ++s) {
      int so = (w * 2 + s) * 512;
      gld16(srcK + so + l * 8, &sK[0][so]);
      gld16(srcV + so + l * 8, &sV[0][so]);
    }
  }
  int avc[8];
#pragma unroll
  for (int nt = 0; nt < 2; ++nt)
#pragma unroll
    for (int q = 0; q < 4; ++q)
      avc[nt * 4 + q] = adj[arow[q] + jt0 * 32 + nt * 16 + lr];
  __syncthreads();

  for (int t = 0; t < T; ++t) {
    const int cur = t & 1;
    int avn[8];
    if (t + 1 < T) {  // stage next tile + prefetch next adj
      const int jn = jt0 + t + 1;
      const unsigned short* srcK = hQf + (size_t)jn * 8192;
      const unsigned short* srcV = hnV + (size_t)jn * 8192;
#pragma unroll
      for (int s = 0; s < 2; ++s) {
        int so = (w * 2 + s) * 512;
        gld16(srcK + so + l * 8, &sK[cur ^ 1][so]);
        gld16(srcV + so + l * 8, &sV[cur ^ 1][so]);
      }
#pragma unroll
      for (int nt = 0; nt < 2; ++nt)
#pragma unroll
        for (int q = 0; q < 4; ++q)
          avn[nt * 4 + q] = adj[arow[q] + jn * 32 + nt * 16 + lr];
    }

    // ---- S = Q . K^T (K=256) ----
    f32x4 S2[2];
    S2[0] = (f32x4){0.f, 0.f, 0.f, 0.f};
    S2[1] = (f32x4){0.f, 0.f, 0.f, 0.f};
#pragma unroll
    for (int kk = 0; kk < 8; ++kk)
#pragma unroll
      for (int nt = 0; nt < 2; ++nt) {
        short8 bf = *(const short8*)(&sK[cur][(nt * 8 + kk) * 512 + l * 8]);
        S2[nt] = mfma16(qf[kk], bf, S2[nt]);
      }

    // ---- masked online softmax (base-2) with defer-max ----
    float sv0[4], sv1[4], mt[4];
#pragma unroll
    for (int q = 0; q < 4; ++q) {
      sv0[q] = avc[q] ? S2[0][q] * c1 : NEGB;
      sv1[q] = avc[4 + q] ? S2[1][q] * c1 : NEGB;
      mt[q] = fmaxf(sv0[q], sv1[q]);
    }
#pragma unroll
    for (int q = 0; q < 4; ++q)
#pragma unroll
      for (int off = 1; off < 16; off <<= 1)
        mt[q] = fmaxf(mt[q], __shfl_xor(mt[q], off));

    bool need = (mt[0] > m2[0] + 8.f) | (mt[1] > m2[1] + 8.f) |
                (mt[2] > m2[2] + 8.f) | (mt[3] > m2[3] + 8.f);
    if (__any(need)) {  // full rescale path
      float fac[4];
#pragma unroll
      for (int q = 0; q < 4; ++q) {
        float mn = fmaxf(m2[q], mt[q]);
        fac[q] = __builtin_amdgcn_exp2f(m2[q] - mn);
        sv0[q] = __builtin_amdgcn_exp2f(sv0[q] - mn);
        sv1[q] = __builtin_amdgcn_exp2f(sv1[q] - mn);
        m2[q] = mn;
      }
      float rs[4];
#pragma unroll
      for (int q = 0; q < 4; ++q) {
        rs[q] = sv0[q] + sv1[q];
#pragma unroll
        for (int off = 1; off < 16; off <<= 1) rs[q] += __shfl_xor(rs[q], off);
        lsum[q] = lsum[q] * fac[q] + rs[q];
      }
#pragma unroll
      for (int nt = 0; nt < 16; ++nt)
#pragma unroll
        for (int q = 0; q < 4; ++q) Oacc[nt][q] *= fac[q];
    } else {  // defer: max unchanged, P bounded by 2^8, no O rescale
      float rs[4];
#pragma unroll
      for (int q = 0; q < 4; ++q) {
        sv0[q] = __builtin_amdgcn_exp2f(sv0[q] - m2[q]);
        sv1[q] = __builtin_amdgcn_exp2f(sv1[q] - m2[q]);
        rs[q] = sv0[q] + sv1[q];
#pragma unroll
        for (int off = 1; off < 16; off <<= 1) rs[q] += __shfl_xor(rs[q], off);
        lsum[q] += rs[q];
      }
    }

    // ---- P (C layout) -> per-wave LDS -> A layout; PV ----
#pragma unroll
    for (int q = 0; q < 4; ++q) {
      sP[w][lg * 4 + q][lr] = f2bf(sv0[q]);
      sP[w][lg * 4 + q][16 + lr] = f2bf(sv1[q]);
    }
    short8 pa = *(const short8*)(&sP[w][lr][lg * 8]);
#pragma unroll
    for (int cnt = 0; cnt < 16; ++cnt) {
      short8 vf = *(const short8*)(&sV[cur][cnt * 512 + l * 8]);
      Oacc[cnt] = mfma16(pa, vf, Oacc[cnt]);
    }

#pragma unroll
    for (int x = 0; x < 8; ++x) avc[x] = avn[x];
    __syncthreads();  // drains next-stage vmcnt + protects buffers
  }

  // ---- write chunk partials (bf16 O, f32 m/l) ----
#pragma unroll
  for (int q = 0; q < 4; ++q) {
    int row = r0 + lg * 4 + q;
    if (lr == 0) {
      pm[(size_t)c * NN + row] = m2[q];
      pl[(size_t)c * NN + row] = lsum[q];
    }
  }
#pragma unroll
  for (int cnt = 0; cnt < 16; ++cnt)
#pragma unroll
    for (int q = 0; q < 4; ++q) {
      int row = r0 + lg * 4 + q;
      pO[((size_t)c * NN + row) * DD + cnt * 16 + lr] = f2bf(Oacc[cnt][q]);
    }
}

// ---- combine chunks + epilogue: one block per row -------------------------
__global__ __launch_bounds__(256) void comb_k(const float* __restrict__ pm,
                                              const float* __restrict__ pl,
                                              const unsigned short* __restrict__ pO,
                                              const unsigned short* __restrict__ hnb,
                                              const int* __restrict__ kptr,
                                              float* __restrict__ out, int S) {
  const int row = blockIdx.x, col = threadIdx.x;
  const int kid = *kptr;
  float v = bf2f(hnb[(size_t)row * DD + col]);
  float res;
  if (row < kid) {
    res = v;
  } else {
    float M = NEGB;
    for (int cc = 0; cc < S; ++cc) M = fmaxf(M, pm[(size_t)cc * NN + row]);
    float L = 0.f, acc = 0.f;
    for (int cc = 0; cc < S; ++cc) {
      float f = __builtin_amdgcn_exp2f(pm[(size_t)cc * NN + row] - M);
      L += pl[(size_t)cc * NN + row] * f;
      acc += bf2f(pO[((size_t)cc * NN + row) * DD + col]) * f;
    }
    res = acc * (0.5f / L) + 0.5f * v;
  }
  out[(size_t)row * DD + col] = fmaxf(res, 0.f);
}

extern "C" void kernel_launch(void* const* d_in, const int* in_sizes, int n_in,
                              void* d_out, int out_size, void* d_ws, size_t ws_size,
                              hipStream_t stream) {
  const float* h = (const float*)d_in[0];
  const int* adj = (const int*)d_in[1];
  const float* W = (const float*)d_in[2];
  const float* b = (const float*)d_in[3];
  float* out = (float*)d_out;

  char* ws = (char*)d_ws;
  const size_t MB4 = (size_t)NN * DD * 2;  // 4 MiB
  int* kbuf = (int*)ws;
  unsigned short* hQf = (unsigned short*)(ws + 256);
  unsigned short* hnb = (unsigned short*)(ws + 256 + MB4);
  unsigned short* hnV = (unsigned short*)(ws + 256 + 2 * MB4);
  unsigned short* Wf = (unsigned short*)(ws + 256 + 3 * MB4);  // 128 KiB
  char* dyn = ws + 256 + 3 * MB4 + (256 << 10);

  size_t fixed = 256 + 3 * MB4 + (256 << 10);
  int S = 8;
  while (S > 1 && fixed + (size_t)S * NN * (DD * 2 + 8) > ws_size) S >>= 1;
  const int T = 256 / S;

  float* pm = (float*)dyn;
  float* pl = pm + (size_t)S * NN;
  unsigned short* pO = (unsigned short*)(pl + (size_t)S * NN);

  hipMemsetAsync(kbuf, 0, 4, stream);
  hipLaunchKernelGGL(count_k, dim3(32), dim3(256), 0, stream, adj, kbuf);
  hipLaunchKernelGGL(conv_h, dim3(2048), dim3(256), 0, stream, h, hQf);
  hipLaunchKernelGGL(pack_wf, dim3(32), dim3(256), 0, stream, W, Wf);
  hipLaunchKernelGGL(hnew_k, dim3(NN / 64), dim3(256), 0, stream, hQf, Wf, b, hnb, hnV);
  hipLaunchKernelGGL(attn_part, dim3(NN / 128, S), dim3(512), 0, stream,
                     hQf, hnV, adj, kbuf, pm, pl, pO, T);
  hipLaunchKernelGGL(comb_k, dim3(NN), dim3(256), 0, stream, pm, pl, pO, hnb, kbuf, out, S);
}